// Round 10
// baseline (431.345 us; speedup 1.0000x reference)
//
#include <hip/hip_runtime.h>
#include <hip/hip_cooperative_groups.h>
namespace cg = cooperative_groups;

// GATConv single layer. N=50000, E=800000 (+N self loops), IN=128, H*C=128.
//
// R10 = R8 skeleton with the LEAN tail (scan+scatter+agg) merged into one
// cooperative kernel. R9's lesson: the MFMA GEMM's register payload killed
// the coop-launch occupancy validation — so the GEMM stays in its own
// (non-coop) kernel and only the low-VGPR chain is cooperative.
// Pipeline (all on `stream`):
//   memset deg
//   K1 gemm_hist : blocks[0,640) h_bf16=x@W via mfma_f32_16x16x32_bf16
//                  (A,B converted fp32->bf16 in-register; fused a_src/a_dst
//                  epilogue). blocks[640,1024): ppos[e]=deg[dst]++ (rebalanced
//                  640/384: hist is atomic-bound, gemm was the R8 critical path).
//   K2 gat_tail  : cooperative, 1024 blocks x 256 thr, grid.sync between:
//       P1 blocks[0,49): 1-barrier shfl exclusive scan of (deg+1)
//       P2 all: wave-scan bsum in LDS; scatter csr_src(u16) + row_st + self-loop
//       P3 all: agg — wave/dst-node, 64-edge batches, 4 head weights per edge
//          into LDS (4 exp/lane), 4 quarter-waves, next-group prefetch,
//          fused /denom + bias.
// No segment-max: logits are O(7), exp() safe in fp32; exp(e)/sum == softmax.

constexpr int N_NODES = 50000;
constexpr int N_EDGES = 800000;
constexpr int E_TOT   = N_EDGES + N_NODES;  // 850000
constexpr int HC      = 128;
constexpr float NEG_SLOPE = 0.2f;
constexpr int M_TILES = N_NODES / 16;       // 3125
constexpr int NB_GEMM = 640;
constexpr int NB_HIST = 384;
constexpr int NBLK    = 1024;               // coop grid: 4 blocks/CU x 256 CU
constexpr int SCAN_BLOCKS = (N_NODES + 1023) / 1024;  // 49

typedef short short8 __attribute__((ext_vector_type(8)));
typedef float f32x4  __attribute__((ext_vector_type(4)));

__device__ inline unsigned short f2bf(float f) {   // RTNE
    unsigned int u = __float_as_uint(f);
    u += 0x7FFF + ((u >> 16) & 1);
    return (unsigned short)(u >> 16);
}

// ---- K1: MFMA GEMM (+att-dot epilogue) overlapped with edge histogram ----

__global__ __launch_bounds__(256) void gemm_hist(
    const float* __restrict__ x,             // [N,128] fp32
    const float* __restrict__ W,             // [k:128][n:128] fp32
    const float* __restrict__ att_src, const float* __restrict__ att_dst,
    const int* __restrict__ edst,
    unsigned short* __restrict__ hb,         // [N,128] bf16
    float* __restrict__ a_src, float* __restrict__ a_dst,
    int* __restrict__ deg, unsigned short* __restrict__ ppos)
{
    if (blockIdx.x >= NB_GEMM) {
        // ---------------- histogram part ----------------
        const int t0 = (blockIdx.x - NB_GEMM) * 256 + threadIdx.x;
        for (int e = t0; e < N_EDGES; e += NB_HIST * 256)
            ppos[e] = (unsigned short)atomicAdd(&deg[edst[e]], 1);
        return;
    }
    // ---------------- GEMM part ----------------
    const int wave = threadIdx.x >> 6;
    const int lane = threadIdx.x & 63;
    const int n0   = (wave & 1) * 64;        // n-strip per wave
    const int l15  = lane & 15;
    const int quad = lane >> 4;

    // B frags direct from fp32 W (64 KB, L2-hot; amortized over ~2.4 tiles):
    // B[k=ks*32+quad*8+j][n=n0+16t+l15] = W[k*128+n]
    short8 bfrag[4][4];
    #pragma unroll
    for (int t = 0; t < 4; ++t)
        #pragma unroll
        for (int ks = 0; ks < 4; ++ks) {
            short8 b;
            #pragma unroll
            for (int j = 0; j < 8; ++j)
                b[j] = (short)f2bf(W[(ks * 32 + quad * 8 + j) * 128 + n0 + t * 16 + l15]);
            bfrag[t][ks] = b;
        }

    float asw[4], adw[4];                    // att weights, col = n0+t*16+l15
    #pragma unroll
    for (int t = 0; t < 4; ++t) {
        asw[t] = att_src[n0 + t * 16 + l15];
        adw[t] = att_dst[n0 + t * 16 + l15];
    }

    for (int mt = blockIdx.x * 2 + (wave >> 1); mt < M_TILES; mt += NB_GEMM * 2) {
        const int m0 = mt * 16;
        short8 afrag[4];                     // A[m=m0+l15][k=ks*32+quad*8+j]
        #pragma unroll
        for (int ks = 0; ks < 4; ++ks) {
            const float4 u0 = *(const float4*)&x[(size_t)(m0 + l15) * 128 + ks * 32 + quad * 8];
            const float4 u1 = *(const float4*)&x[(size_t)(m0 + l15) * 128 + ks * 32 + quad * 8 + 4];
            short8 a;
            a[0] = (short)f2bf(u0.x); a[1] = (short)f2bf(u0.y);
            a[2] = (short)f2bf(u0.z); a[3] = (short)f2bf(u0.w);
            a[4] = (short)f2bf(u1.x); a[5] = (short)f2bf(u1.y);
            a[6] = (short)f2bf(u1.z); a[7] = (short)f2bf(u1.w);
            afrag[ks] = a;
        }

        f32x4 acc[4];
        #pragma unroll
        for (int t = 0; t < 4; ++t) acc[t] = (f32x4){0.f, 0.f, 0.f, 0.f};

        #pragma unroll
        for (int ks = 0; ks < 4; ++ks)
            #pragma unroll
            for (int t = 0; t < 4; ++t)
                acc[t] = __builtin_amdgcn_mfma_f32_16x16x32_bf16(afrag[ks], bfrag[t][ks], acc[t], 0, 0, 0);

        // C/D: row = m0 + quad*4 + r, col = n0 + t*16 + l15
        #pragma unroll
        for (int t = 0; t < 4; ++t)
            #pragma unroll
            for (int r = 0; r < 4; ++r)
                hb[(m0 + quad * 4 + r) * 128 + n0 + t * 16 + l15] = f2bf(acc[t][r]);

        // fused attention dots: per lane, head g = n0/32 + (t>>1)
        float hs[2][4] = {{0.f,0.f,0.f,0.f},{0.f,0.f,0.f,0.f}};
        float hd[2][4] = {{0.f,0.f,0.f,0.f},{0.f,0.f,0.f,0.f}};
        #pragma unroll
        for (int t = 0; t < 4; ++t)
            #pragma unroll
            for (int r = 0; r < 4; ++r) {
                hs[t >> 1][r] += acc[t][r] * asw[t];
                hd[t >> 1][r] += acc[t][r] * adw[t];
            }
        #pragma unroll
        for (int off = 1; off < 16; off <<= 1)
            #pragma unroll
            for (int g = 0; g < 2; ++g)
                #pragma unroll
                for (int r = 0; r < 4; ++r) {
                    hs[g][r] += __shfl_xor(hs[g][r], off);
                    hd[g][r] += __shfl_xor(hd[g][r], off);
                }
        if (l15 == 0) {
            const int hb0 = n0 >> 5;         // first head of this strip
            #pragma unroll
            for (int g = 0; g < 2; ++g)
                #pragma unroll
                for (int r = 0; r < 4; ++r) {
                    a_src[(m0 + quad * 4 + r) * 4 + hb0 + g] = hs[g][r];
                    a_dst[(m0 + quad * 4 + r) * 4 + hb0 + g] = hd[g][r];
                }
        }
    }
}

// ---- K2: cooperative lean tail — scan, scatter, aggregate ----

__global__ __launch_bounds__(256, 4) void gat_tail(
    const int* __restrict__ deg,
    const int* __restrict__ esrc, const int* __restrict__ edst,
    const unsigned short* __restrict__ ppos,
    int* __restrict__ partial, int* __restrict__ bsum,
    int* __restrict__ row_st, unsigned short* __restrict__ csr_src,
    const unsigned short* __restrict__ hb, const float* __restrict__ a_src,
    const float* __restrict__ a_dst, const float* __restrict__ bias,
    float* __restrict__ out)
{
    cg::grid_group grid = cg::this_grid();
    const int blk  = blockIdx.x;
    const int tid  = threadIdx.x;
    const int wave = tid >> 6;
    const int lane = tid & 63;
    __shared__ int smi[1024];                // 4 KB: wsum / sb / agg weights
    float* smf = (float*)smi;

    // ---------------- P1: exclusive scan of (deg+1), 49 blocks ----------
    if (blk < SCAN_BLOCKS) {
        const int base = blk * 1024 + tid * 4;
        int d0 = 0, d1 = 0, d2 = 0, d3 = 0;
        if (base + 3 < N_NODES) {
            const int4 v = *(const int4*)&deg[base];
            d0 = v.x + 1; d1 = v.y + 1; d2 = v.z + 1; d3 = v.w + 1;
        } else {
            if (base + 0 < N_NODES) d0 = deg[base + 0] + 1;
            if (base + 1 < N_NODES) d1 = deg[base + 1] + 1;
            if (base + 2 < N_NODES) d2 = deg[base + 2] + 1;
            if (base + 3 < N_NODES) d3 = deg[base + 3] + 1;
        }
        const int s0 = d0, s1 = s0 + d1, s2 = s1 + d2, s3 = s2 + d3;
        int inc = s3;                        // wave-inclusive scan of totals
        #pragma unroll
        for (int off = 1; off < 64; off <<= 1) {
            const int t = __shfl_up(inc, off);
            if (lane >= off) inc += t;
        }
        if (lane == 63) smi[wave] = inc;
        __syncthreads();
        int wbase = 0;
        for (int k = 0; k < wave; ++k) wbase += smi[k];
        const int tb = wbase + inc - s3;     // exclusive base for this thread
        if (base + 3 < N_NODES) {
            *(int4*)&partial[base] = (int4){tb, tb + s0, tb + s1, tb + s2};
        } else {
            if (base + 0 < N_NODES) partial[base + 0] = tb;
            if (base + 1 < N_NODES) partial[base + 1] = tb + s0;
            if (base + 2 < N_NODES) partial[base + 2] = tb + s1;
            if (base + 3 < N_NODES) partial[base + 3] = tb + s2;
        }
        if (tid == 255) bsum[blk] = wbase + inc;
    }
    grid.sync();

    // ---------------- P2: scatter + row_st finalize (all blocks) --------
    {
        if (tid < 64) {                      // exclusive scan of 49 bsums
            const int v = (tid < SCAN_BLOCKS) ? bsum[tid] : 0;
            int s = v;
            #pragma unroll
            for (int off = 1; off < 64; off <<= 1) {
                const int t = __shfl_up(s, off);
                if (tid >= off) s += t;
            }
            smi[tid] = s - v;                // sb
        }
        __syncthreads();
        for (int idx = blk * 256 + tid; idx < E_TOT; idx += NBLK * 256) {
            if (idx < N_EDGES) {
                const int d = edst[idx];
                csr_src[partial[d] + smi[d >> 10] + 1 + ppos[idx]] = (unsigned short)esrc[idx];
            } else {
                const int i = idx - N_EDGES;             // node domain
                const int r = partial[i] + smi[i >> 10];
                row_st[i] = r;
                csr_src[r] = (unsigned short)i;          // self loop in slot 0
                if (i == 0) row_st[N_NODES] = E_TOT;
            }
        }
    }
    grid.sync();

    // ---------------- P3: aggregation (all blocks, grid-stride) ---------
    float* ws = &smf[wave * 256];            // per-wave weight table
    const int q   = lane >> 4;               // quarter: which edge of the 4
    const int li  = lane & 15;
    const int ch0 = li * 8;                  // 8 channels per lane
    const int hd  = li >> 2;                 // head of my channels (ch0/32)
    for (int nb = blk; nb < N_NODES / 4; nb += NBLK) {
        const int node = nb * 4 + wave;      // N_NODES % 4 == 0
        const float4 ad4 = *(const float4*)&a_dst[node * 4];
        const int p0 = row_st[node], p1 = row_st[node + 1];

        float acc[8] = {0.f,0.f,0.f,0.f,0.f,0.f,0.f,0.f};
        float dsum = 0.f;

        for (int base = p0; base < p1; base += 64) {
            int m = p1 - base; if (m > 64) m = 64;
            int sv = 0;
            if (lane < m) {
                sv = (int)csr_src[base + lane];  // coalesced batch of src ids
                const float4 av = *(const float4*)&a_src[sv * 4];
                float t; float4 w4;
                t = av.x + ad4.x; t = t > 0.f ? t : NEG_SLOPE * t; w4.x = __expf(t);
                t = av.y + ad4.y; t = t > 0.f ? t : NEG_SLOPE * t; w4.y = __expf(t);
                t = av.z + ad4.z; t = t > 0.f ? t : NEG_SLOPE * t; w4.z = __expf(t);
                t = av.w + ad4.w; t = t > 0.f ? t : NEG_SLOPE * t; w4.w = __expf(t);
                *(float4*)&ws[lane * 4] = w4;    // all 4 head weights, my edge
            }
            // software-pipelined: prefetch next 4-edge group's rows (8 rows
            // in flight per wave). Same-wave LDS RAW: lockstep, no barrier.
            const int i0 = (q < m) ? q : 0;
            int s_cur = __shfl(sv, i0);
            uint4 hv = *(const uint4*)&hb[(size_t)s_cur * 128 + ch0];
            for (int j = 0; j < m; j += 4) {
                const int ei  = j + q;
                const int idx = ei < m ? ei : j;     // edge whose row is in hv
                const int ein = ei + 4;
                const int idxn = ein < m ? ein : 0;  // next group (clamped)
                const int s_nxt = __shfl(sv, idxn);
                const uint4 hvn = *(const uint4*)&hb[(size_t)s_nxt * 128 + ch0];
                float w = ws[idx * 4 + hd];
                if (ei >= m) w = 0.f;
                acc[0] += w * __uint_as_float(hv.x << 16);
                acc[1] += w * __uint_as_float(hv.x & 0xFFFF0000u);
                acc[2] += w * __uint_as_float(hv.y << 16);
                acc[3] += w * __uint_as_float(hv.y & 0xFFFF0000u);
                acc[4] += w * __uint_as_float(hv.z << 16);
                acc[5] += w * __uint_as_float(hv.z & 0xFFFF0000u);
                acc[6] += w * __uint_as_float(hv.w << 16);
                acc[7] += w * __uint_as_float(hv.w & 0xFFFF0000u);
                dsum += w;
                hv = hvn;
            }
        }
        // combine the four quarters (disjoint edge subsets, same channels)
        #pragma unroll
        for (int off = 16; off <= 32; off <<= 1) {
            #pragma unroll
            for (int r = 0; r < 8; ++r) acc[r] += __shfl_xor(acc[r], off);
            dsum += __shfl_xor(dsum, off);
        }
        if (q == 0) {
            const float inv = 1.f / dsum;    // dsum >= exp(self) > 0
            const float4 b0 = *(const float4*)&bias[ch0];
            const float4 b1 = *(const float4*)&bias[ch0 + 4];
            float4 o0, o1;
            o0.x = acc[0]*inv + b0.x; o0.y = acc[1]*inv + b0.y;
            o0.z = acc[2]*inv + b0.z; o0.w = acc[3]*inv + b0.w;
            o1.x = acc[4]*inv + b1.x; o1.y = acc[5]*inv + b1.y;
            o1.z = acc[6]*inv + b1.z; o1.w = acc[7]*inv + b1.w;
            *(float4*)&out[(size_t)node * HC + ch0]     = o0;
            *(float4*)&out[(size_t)node * HC + ch0 + 4] = o1;
        }
    }
}

extern "C" void kernel_launch(void* const* d_in, const int* in_sizes, int n_in,
                              void* d_out, int out_size, void* d_ws, size_t ws_size,
                              hipStream_t stream) {
    const float* x       = (const float*)d_in[0];
    const int*   ei      = (const int*)  d_in[1];   // [2,E]: row0=src, row1=dst
    const float* W       = (const float*)d_in[2];
    const float* att_src = (const float*)d_in[3];
    const float* att_dst = (const float*)d_in[4];
    const float* bias    = (const float*)d_in[5];
    float* out = (float*)d_out;

    // ws layout (~18 MB): hb | a_src | a_dst | csr(u16) | ppos(u16) | partial | row_st | deg | bsum
    char* p = (char*)d_ws;
    unsigned short* hb  = (unsigned short*)p; p += (size_t)N_NODES * HC * 2;  // 12.8 MB
    float* a_src = (float*)p; p += (size_t)N_NODES * 4 * 4;                   // 800 KB
    float* a_dst = (float*)p; p += (size_t)N_NODES * 4 * 4;
    unsigned short* csr_src = (unsigned short*)p; p += (size_t)E_TOT * 2;     // 1.7 MB
    unsigned short* ppos    = (unsigned short*)p; p += (size_t)N_EDGES * 2;   // 1.6 MB
    int* partial = (int*)p;   p += N_NODES * 4;
    int* row_st  = (int*)p;   p += (N_NODES + 4) * 4;
    int* deg     = (int*)p;   p += N_NODES * 4;
    int* bsum    = (int*)p;   p += 64 * 4;

    const int* esrc = ei;
    const int* edst = ei + N_EDGES;

    hipMemsetAsync(deg, 0, (size_t)N_NODES * sizeof(int), stream);

    gemm_hist<<<NB_GEMM + NB_HIST, 256, 0, stream>>>(x, W, att_src, att_dst,
                                                     edst, hb, a_src, a_dst, deg, ppos);

    void* args[] = {
        (void*)&deg, (void*)&esrc, (void*)&edst, (void*)&ppos,
        (void*)&partial, (void*)&bsum, (void*)&row_st, (void*)&csr_src,
        (void*)&hb, (void*)&a_src, (void*)&a_dst, (void*)&bias, (void*)&out
    };
    hipLaunchCooperativeKernel((const void*)gat_tail, dim3(NBLK), dim3(256),
                               args, 0, stream);
}

// Round 11
// 175.621 us; speedup vs baseline: 2.4561x; 2.4561x over previous
//
#include <hip/hip_runtime.h>

// GATConv single layer. N=50000, E=800000 (+N self loops), IN=128, H*C=128.
//
// R11 = R8 (best: 170.7us) + wtb precompute folded into the deg-zero init
// kernel (replaces hipMemsetAsync; no extra dispatch). Kills the ~5.2M
// redundant per-block W fp32->bf16 conversions in the gemm.
// R10 lesson: cooperative kernels are ~5x slower for memory-bound phases on
// MI355X (cross-XCD coherence defeats L2) — plain dispatch boundaries are the
// cheap grid barrier. Keep 5 plain dispatches.
// Pipeline (all on `stream`):
//   K0 init       : deg=0 ; wtb[n][k] = bf16(W[k][n])
//   K1 gemm_hist  : blocks[0,512) h_bf16=x@W via mfma_f32_16x16x32_bf16
//                   (A converted in-register, B-frags coalesced short8 from
//                   wtb; fused a_src/a_dst epilogue). blocks[512,1024):
//                   ppos[e]=deg[dst]++ (grid-stride).
//   K2 scan       : 49 blocks, 4 elems/thread, 1-barrier shfl scan -> partial,bsum
//   K3 scatter_fin: per-block wave-scan of bsum; edges: csr(u16); nodes:
//                   row_st finalize + self-loop plant.
//   K4 gat_agg    : wave per dst node; 64-edge coalesced batches; per-edge 4
//                   head weights into LDS (4 exp/lane); 4 quarter-waves, 8
//                   ch/lane, next-group prefetch (8 rows in flight);
//                   fused /denom + bias.
// No segment-max: logits are O(7), exp() safe in fp32; exp(e)/sum == softmax.

constexpr int N_NODES = 50000;
constexpr int N_EDGES = 800000;
constexpr int E_TOT   = N_EDGES + N_NODES;  // 850000
constexpr int HC      = 128;
constexpr float NEG_SLOPE = 0.2f;
constexpr int M_TILES = N_NODES / 16;               // 3125
constexpr int NB_GEMM = 512;
constexpr int NB_HIST = 512;
constexpr int SCAN_BLOCKS = (N_NODES + 1023) / 1024;  // 49

typedef short short8 __attribute__((ext_vector_type(8)));
typedef float f32x4  __attribute__((ext_vector_type(4)));

__device__ inline unsigned short f2bf(float f) {   // RTNE
    unsigned int u = __float_as_uint(f);
    u += 0x7FFF + ((u >> 16) & 1);
    return (unsigned short)(u >> 16);
}

// ---- K0: zero deg + precompute wtb (W transpose + bf16 cast) ----

__global__ __launch_bounds__(256) void init(
    int* __restrict__ deg, const float* __restrict__ W,
    unsigned short* __restrict__ wtb)
{
    const int i = blockIdx.x * 256 + threadIdx.x;
    if (i < 128 * 128) {                             // i = n*128 + k
        const int n = i >> 7, k = i & 127;
        wtb[i] = f2bf(W[k * 128 + n]);               // Wt[n][k] = W[k][n]
    }
    for (int j = i; j < N_NODES; j += 256 * 256) deg[j] = 0;
}

// ---- K1: MFMA GEMM (+att-dot epilogue) overlapped with edge histogram ----

__global__ __launch_bounds__(256) void gemm_hist(
    const float* __restrict__ x,             // [N,128] fp32
    const unsigned short* __restrict__ wtb,  // [n:128][k:128] bf16
    const float* __restrict__ att_src, const float* __restrict__ att_dst,
    const int* __restrict__ edst,
    unsigned short* __restrict__ hb,         // [N,128] bf16
    float* __restrict__ a_src, float* __restrict__ a_dst,
    int* __restrict__ deg, unsigned short* __restrict__ ppos)
{
    if (blockIdx.x >= NB_GEMM) {
        // ---------------- histogram part ----------------
        const int t0 = (blockIdx.x - NB_GEMM) * 256 + threadIdx.x;
        for (int e = t0; e < N_EDGES; e += NB_HIST * 256)
            ppos[e] = (unsigned short)atomicAdd(&deg[edst[e]], 1);
        return;
    }
    // ---------------- GEMM part ----------------
    const int wave = threadIdx.x >> 6;
    const int lane = threadIdx.x & 63;
    const int n0   = (wave & 1) * 64;        // n-strip per wave
    const int l15  = lane & 15;
    const int quad = lane >> 4;

    // B frags: coalesced short8 loads from pre-cast wtb (once per block):
    // B[k=ks*32+quad*8+j][n=n0+16t+l15] = Wt[n][k]
    short8 bfrag[4][4];
    #pragma unroll
    for (int t = 0; t < 4; ++t)
        #pragma unroll
        for (int ks = 0; ks < 4; ++ks)
            bfrag[t][ks] = *(const short8*)&wtb[(n0 + t * 16 + l15) * 128 + ks * 32 + quad * 8];

    float asw[4], adw[4];                    // att weights, col = n0+t*16+l15
    #pragma unroll
    for (int t = 0; t < 4; ++t) {
        asw[t] = att_src[n0 + t * 16 + l15];
        adw[t] = att_dst[n0 + t * 16 + l15];
    }

    for (int mt = blockIdx.x * 2 + (wave >> 1); mt < M_TILES; mt += NB_GEMM * 2) {
        const int m0 = mt * 16;
        short8 afrag[4];                     // A[m=m0+l15][k=ks*32+quad*8+j]
        #pragma unroll
        for (int ks = 0; ks < 4; ++ks) {
            const float4 u0 = *(const float4*)&x[(size_t)(m0 + l15) * 128 + ks * 32 + quad * 8];
            const float4 u1 = *(const float4*)&x[(size_t)(m0 + l15) * 128 + ks * 32 + quad * 8 + 4];
            short8 a;
            a[0] = (short)f2bf(u0.x); a[1] = (short)f2bf(u0.y);
            a[2] = (short)f2bf(u0.z); a[3] = (short)f2bf(u0.w);
            a[4] = (short)f2bf(u1.x); a[5] = (short)f2bf(u1.y);
            a[6] = (short)f2bf(u1.z); a[7] = (short)f2bf(u1.w);
            afrag[ks] = a;
        }

        f32x4 acc[4];
        #pragma unroll
        for (int t = 0; t < 4; ++t) acc[t] = (f32x4){0.f, 0.f, 0.f, 0.f};

        #pragma unroll
        for (int ks = 0; ks < 4; ++ks)
            #pragma unroll
            for (int t = 0; t < 4; ++t)
                acc[t] = __builtin_amdgcn_mfma_f32_16x16x32_bf16(afrag[ks], bfrag[t][ks], acc[t], 0, 0, 0);

        // C/D: row = m0 + quad*4 + r, col = n0 + t*16 + l15
        #pragma unroll
        for (int t = 0; t < 4; ++t)
            #pragma unroll
            for (int r = 0; r < 4; ++r)
                hb[(m0 + quad * 4 + r) * 128 + n0 + t * 16 + l15] = f2bf(acc[t][r]);

        // fused attention dots: per lane, head g = n0/32 + (t>>1)
        float hs[2][4] = {{0.f,0.f,0.f,0.f},{0.f,0.f,0.f,0.f}};
        float hd[2][4] = {{0.f,0.f,0.f,0.f},{0.f,0.f,0.f,0.f}};
        #pragma unroll
        for (int t = 0; t < 4; ++t)
            #pragma unroll
            for (int r = 0; r < 4; ++r) {
                hs[t >> 1][r] += acc[t][r] * asw[t];
                hd[t >> 1][r] += acc[t][r] * adw[t];
            }
        #pragma unroll
        for (int off = 1; off < 16; off <<= 1)
            #pragma unroll
            for (int g = 0; g < 2; ++g)
                #pragma unroll
                for (int r = 0; r < 4; ++r) {
                    hs[g][r] += __shfl_xor(hs[g][r], off);
                    hd[g][r] += __shfl_xor(hd[g][r], off);
                }
        if (l15 == 0) {
            const int hb0 = n0 >> 5;         // first head of this strip
            #pragma unroll
            for (int g = 0; g < 2; ++g)
                #pragma unroll
                for (int r = 0; r < 4; ++r) {
                    a_src[(m0 + quad * 4 + r) * 4 + hb0 + g] = hs[g][r];
                    a_dst[(m0 + quad * 4 + r) * 4 + hb0 + g] = hd[g][r];
                }
        }
    }
}

// ---- K2: 1-barrier shfl exclusive scan of (deg+1), 4 elems/thread ----

__global__ __launch_bounds__(256) void scan(
    const int* __restrict__ deg, int* __restrict__ partial, int* __restrict__ bsum)
{
    __shared__ int wsum[4];
    const int tid  = threadIdx.x;
    const int lane = tid & 63;
    const int wv   = tid >> 6;
    const int base = blockIdx.x * 1024 + tid * 4;
    int d0 = 0, d1 = 0, d2 = 0, d3 = 0;
    if (base + 3 < N_NODES) {
        const int4 v = *(const int4*)&deg[base];
        d0 = v.x + 1; d1 = v.y + 1; d2 = v.z + 1; d3 = v.w + 1;
    } else {
        if (base + 0 < N_NODES) d0 = deg[base + 0] + 1;
        if (base + 1 < N_NODES) d1 = deg[base + 1] + 1;
        if (base + 2 < N_NODES) d2 = deg[base + 2] + 1;
        if (base + 3 < N_NODES) d3 = deg[base + 3] + 1;
    }
    const int s0 = d0, s1 = s0 + d1, s2 = s1 + d2, s3 = s2 + d3;
    int inc = s3;                            // wave-inclusive scan of totals
    #pragma unroll
    for (int off = 1; off < 64; off <<= 1) {
        const int t = __shfl_up(inc, off);
        if (lane >= off) inc += t;
    }
    if (lane == 63) wsum[wv] = inc;
    __syncthreads();
    int wbase = 0;
    for (int k = 0; k < wv; ++k) wbase += wsum[k];
    const int tb = wbase + inc - s3;         // exclusive base for this thread
    if (base + 3 < N_NODES) {
        *(int4*)&partial[base] = (int4){tb, tb + s0, tb + s1, tb + s2};
    } else {
        if (base + 0 < N_NODES) partial[base + 0] = tb;
        if (base + 1 < N_NODES) partial[base + 1] = tb + s0;
        if (base + 2 < N_NODES) partial[base + 2] = tb + s1;
        if (base + 3 < N_NODES) partial[base + 3] = tb + s2;
    }
    if (tid == 255) bsum[blockIdx.x] = wbase + inc;
}

// ---- K3: scatter edges + finalize row_start (bsum scan per block) ----

__global__ __launch_bounds__(256) void scatter_fin(
    const int* __restrict__ esrc, const int* __restrict__ edst,
    const int* __restrict__ partial, const int* __restrict__ bsum,
    const unsigned short* __restrict__ ppos,
    int* __restrict__ row_st, unsigned short* __restrict__ csr_src)
{
    __shared__ int sb[64];
    if (threadIdx.x < 64) {                  // wave 0: exclusive scan of bsum
        const int v = (threadIdx.x < SCAN_BLOCKS) ? bsum[threadIdx.x] : 0;
        int s = v;
        #pragma unroll
        for (int off = 1; off < 64; off <<= 1) {
            const int t = __shfl_up(s, off);
            if ((int)threadIdx.x >= off) s += t;
        }
        sb[threadIdx.x] = s - v;
    }
    __syncthreads();
    const int idx = blockIdx.x * 256 + threadIdx.x;
    if (idx < N_EDGES) {
        const int d = edst[idx];
        csr_src[partial[d] + sb[d >> 10] + 1 + ppos[idx]] = (unsigned short)esrc[idx];
    } else if (idx < E_TOT) {
        const int i = idx - N_EDGES;                 // node domain
        const int r = partial[i] + sb[i >> 10];
        row_st[i] = r;
        csr_src[r] = (unsigned short)i;              // self loop in slot 0
        if (i == 0) row_st[N_NODES] = E_TOT;
    }
}

// ---- K4: aggregation — wave/node, 4 edges in flight + prefetch ----

__global__ __launch_bounds__(256) void gat_agg(
    const int* __restrict__ row_start, const unsigned short* __restrict__ csr_src,
    const unsigned short* __restrict__ hb, const float* __restrict__ a_src,
    const float* __restrict__ a_dst, const float* __restrict__ bias,
    float* __restrict__ out)
{
    __shared__ float ws[4][256];             // [wave][edge*4 + head]
    const int wv = threadIdx.x >> 6;
    const int node = blockIdx.x * 4 + wv;
    if (node >= N_NODES) return;
    const int lane = threadIdx.x & 63;
    const int q    = lane >> 4;              // quarter: which edge of the 4
    const int li   = lane & 15;
    const int ch0  = li * 8;                 // 8 channels per lane
    const int hd   = li >> 2;                // head of my channels (ch0/32)
    const float4 ad4 = *(const float4*)&a_dst[node * 4];
    const int p0 = row_start[node], p1 = row_start[node + 1];

    float acc[8] = {0.f,0.f,0.f,0.f,0.f,0.f,0.f,0.f};
    float dsum = 0.f;

    for (int base = p0; base < p1; base += 64) {
        int m = p1 - base; if (m > 64) m = 64;
        int sv = 0;
        if (lane < m) {
            sv = (int)csr_src[base + lane];  // coalesced batch of src ids
            const float4 av = *(const float4*)&a_src[sv * 4];
            float t; float4 w4;
            t = av.x + ad4.x; t = t > 0.f ? t : NEG_SLOPE * t; w4.x = __expf(t);
            t = av.y + ad4.y; t = t > 0.f ? t : NEG_SLOPE * t; w4.y = __expf(t);
            t = av.z + ad4.z; t = t > 0.f ? t : NEG_SLOPE * t; w4.z = __expf(t);
            t = av.w + ad4.w; t = t > 0.f ? t : NEG_SLOPE * t; w4.w = __expf(t);
            *(float4*)&ws[wv][lane * 4] = w4; // all 4 head weights for my edge
        }
        // software-pipelined: prefetch next 4-edge group's h rows while
        // accumulating the current group (8 rows in flight per wave).
        const int i0 = (q < m) ? q : 0;
        int s_cur = __shfl(sv, i0);
        uint4 hv = *(const uint4*)&hb[(size_t)s_cur * 128 + ch0];
        for (int j = 0; j < m; j += 4) {
            const int ei  = j + q;
            const int idx = ei < m ? ei : j;     // edge whose row is in hv
            const int ein = ei + 4;
            const int idxn = ein < m ? ein : 0;  // next group's edge (clamped)
            const int s_nxt = __shfl(sv, idxn);
            const uint4 hvn = *(const uint4*)&hb[(size_t)s_nxt * 128 + ch0];
            float w = ws[wv][idx * 4 + hd];
            if (ei >= m) w = 0.f;
            acc[0] += w * __uint_as_float(hv.x << 16);
            acc[1] += w * __uint_as_float(hv.x & 0xFFFF0000u);
            acc[2] += w * __uint_as_float(hv.y << 16);
            acc[3] += w * __uint_as_float(hv.y & 0xFFFF0000u);
            acc[4] += w * __uint_as_float(hv.z << 16);
            acc[5] += w * __uint_as_float(hv.z & 0xFFFF0000u);
            acc[6] += w * __uint_as_float(hv.w << 16);
            acc[7] += w * __uint_as_float(hv.w & 0xFFFF0000u);
            dsum += w;
            hv = hvn;
        }
    }
    // combine the four quarters (disjoint edge subsets, same channels)
    #pragma unroll
    for (int off = 16; off <= 32; off <<= 1) {
        #pragma unroll
        for (int r = 0; r < 8; ++r) acc[r] += __shfl_xor(acc[r], off);
        dsum += __shfl_xor(dsum, off);
    }
    if (q == 0) {
        const float inv = 1.f / dsum;        // dsum >= exp(self) > 0
        const float4 b0 = *(const float4*)&bias[ch0];
        const float4 b1 = *(const float4*)&bias[ch0 + 4];
        float4 o0, o1;
        o0.x = acc[0]*inv + b0.x; o0.y = acc[1]*inv + b0.y;
        o0.z = acc[2]*inv + b0.z; o0.w = acc[3]*inv + b0.w;
        o1.x = acc[4]*inv + b1.x; o1.y = acc[5]*inv + b1.y;
        o1.z = acc[6]*inv + b1.z; o1.w = acc[7]*inv + b1.w;
        *(float4*)&out[(size_t)node * HC + ch0]     = o0;
        *(float4*)&out[(size_t)node * HC + ch0 + 4] = o1;
    }
}

extern "C" void kernel_launch(void* const* d_in, const int* in_sizes, int n_in,
                              void* d_out, int out_size, void* d_ws, size_t ws_size,
                              hipStream_t stream) {
    const float* x       = (const float*)d_in[0];
    const int*   ei      = (const int*)  d_in[1];   // [2,E]: row0=src, row1=dst
    const float* W       = (const float*)d_in[2];
    const float* att_src = (const float*)d_in[3];
    const float* att_dst = (const float*)d_in[4];
    const float* bias    = (const float*)d_in[5];
    float* out = (float*)d_out;

    // ws layout (~18 MB): hb | wtb | a_src | a_dst | csr(u16) | ppos(u16) | partial | row_st | deg | bsum
    char* p = (char*)d_ws;
    unsigned short* hb  = (unsigned short*)p; p += (size_t)N_NODES * HC * 2;  // 12.8 MB
    unsigned short* wtb = (unsigned short*)p; p += 128 * 128 * 2;             // 32 KB
    float* a_src = (float*)p; p += (size_t)N_NODES * 4 * 4;                   // 800 KB
    float* a_dst = (float*)p; p += (size_t)N_NODES * 4 * 4;
    unsigned short* csr_src = (unsigned short*)p; p += (size_t)E_TOT * 2;     // 1.7 MB
    unsigned short* ppos    = (unsigned short*)p; p += (size_t)N_EDGES * 2;   // 1.6 MB
    int* partial = (int*)p;   p += N_NODES * 4;
    int* row_st  = (int*)p;   p += (N_NODES + 4) * 4;
    int* deg     = (int*)p;   p += N_NODES * 4;
    int* bsum    = (int*)p;

    const int* esrc = ei;
    const int* edst = ei + N_EDGES;

    init       <<<256, 256, 0, stream>>>(deg, W, wtb);
    gemm_hist  <<<NB_GEMM + NB_HIST, 256, 0, stream>>>(x, wtb, att_src, att_dst,
                                                       edst, hb, a_src, a_dst, deg, ppos);
    scan       <<<SCAN_BLOCKS, 256, 0, stream>>>(deg, partial, bsum);
    scatter_fin<<<(E_TOT + 255) / 256, 256, 0, stream>>>(esrc, edst, partial, bsum,
                                                         ppos, row_st, csr_src);
    gat_agg    <<<(N_NODES + 3) / 4, 256, 0, stream>>>(row_st, csr_src, hb, a_src,
                                                       a_dst, bias, out);
}